// Round 6
// baseline (5213.505 us; speedup 1.0000x reference)
//
#include <hip/hip_runtime.h>

#define NB 32
#define NZ 100
#define ST 20
#define HID 128
#define HW 32
#define PIX 1024
#define STEPS 64
#define TH 0.1f
#define SCL 0.0625f     // 1/16 stored-value scaling (power of 2)
#define ISCL 16.0f
#define NBLOCKS 512

typedef _Float16 half8  __attribute__((ext_vector_type(8)));
typedef _Float16 half4v __attribute__((ext_vector_type(4)));
typedef float    floatx4 __attribute__((ext_vector_type(4)));

// perceive GEMM K layout: k = q*24 + c  (q=dy*3+dx in 0..8, c in 0..23, pad from 20)
#define NKS1 7
#define PK 136          // perc/hid LDS row stride

// ---------------------------------------------------------------------------
__global__ __launch_bounds__(64) void init_state_kernel(
    const float* __restrict__ z, const float* __restrict__ w1,
    const float* __restrict__ b1, const float* __restrict__ w2,
    const float* __restrict__ b2, float* __restrict__ B,
    unsigned char* __restrict__ M)
{
    __shared__ float zs[NZ];
    __shared__ float h1[50];
    const int n = blockIdx.x;
    const int t = threadIdx.x;
    for (int i = t; i < NZ; i += 64) zs[i] = z[n * NZ + i];
    __syncthreads();
    if (t < 50) {
        float a = b1[t];
        for (int i = 0; i < NZ; ++i) a += w1[t * NZ + i] * zs[i];
        h1[t] = fmaxf(a, 0.f);
    }
    __syncthreads();
    if (t < ST - 1) {
        float a = b2[t];
        for (int j = 0; j < 50; ++j) a += w2[t * 50 + j] * h1[j];
        B[n * ST * PIX + (t + 1) * PIX + 16 * HW + 16] = a;
    }
    if (t == 63) B[n * ST * PIX + 16 * HW + 16] = 0.5f;
    for (int i = t; i < PIX; i += 64) M[n * PIX + i] = 1;
}

// ---------------------------------------------------------------------------
// Repack weights into MFMA A-fragment order as fp16 hi/lo pairs. (unchanged)
__global__ __launch_bounds__(256) void repack_kernel(
    const float* __restrict__ Wp, const float* __restrict__ W1,
    const float* __restrict__ W2,
    _Float16* __restrict__ WpRh, _Float16* __restrict__ WpRl,
    _Float16* __restrict__ W1Rh, _Float16* __restrict__ W1Rl,
    _Float16* __restrict__ W2Rh, _Float16* __restrict__ W2Rl)
{
    int e = blockIdx.x * 256 + threadIdx.x;
    if (e < 28672) {
        int j = e & 7, lane = (e >> 3) & 63, t2 = e >> 9;   // t2 = w*7+ks
        int ks = t2 % 7, w = t2 / 7;
        int m = w * 16 + (lane & 15);
        int k = ks * 32 + ((lane >> 4) << 3) + j;
        int q = k / 24, c = k - q * 24;
        float v = (q < 9 && c < ST) ? Wp[m * 180 + c * 9 + q] : 0.f;
        _Float16 hi = (_Float16)v;
        WpRh[e] = hi; WpRl[e] = (_Float16)(v - (float)hi);
    } else if (e < 45056) {
        int e2 = e - 28672;
        int j = e2 & 7, lane = (e2 >> 3) & 63, t2 = e2 >> 9; // t2 = w*4+ks
        int ks = t2 & 3, w = t2 >> 2;
        int m = w * 16 + (lane & 15);
        int k = ks * 32 + ((lane >> 4) << 3) + j;
        float v = W1[m * 128 + k];
        _Float16 hi = (_Float16)v;
        W1Rh[e2] = hi; W1Rl[e2] = (_Float16)(v - (float)hi);
    } else if (e < 49152) {
        int e3 = e - 45056;
        int j = e3 & 7, lane = (e3 >> 3) & 63, t2 = e3 >> 9; // t2 = mt*4+ks
        int ks = t2 & 3, mt = t2 >> 2;
        int m = mt * 16 + (lane & 15);
        int k = ks * 32 + ((lane >> 4) << 3) + j;
        float v = (m < ST) ? W2[m * 128 + k] : 0.f;
        _Float16 hi = (_Float16)v;
        W2Rh[e3] = hi; W2Rl[e3] = (_Float16)(v - (float)hi);
    }
}

// ---------------------------------------------------------------------------
// Persistent fused CA: 512 blocks x 256 thr (4 waves), all 64 steps inside,
// per-step device-scope grid barrier. Each block owns one (strip, image).
// Wave wv: m-tiles {2wv, 2wv+1}, all 4 n-tiles. G1/G2 hi A-frags register-
// resident across all steps; lo A-frags + G3 weights streamed from L2.
__global__ __launch_bounds__(256, 2) void ca_persistent_kernel(
    float* __restrict__ B0g, float* __restrict__ B1g,
    unsigned char* __restrict__ M0g, unsigned char* __restrict__ M1g,
    const _Float16* __restrict__ WpRh, const _Float16* __restrict__ WpRl,
    const float* __restrict__ bp,
    const _Float16* __restrict__ W1Rh, const _Float16* __restrict__ W1Rl,
    const float* __restrict__ b1,
    const _Float16* __restrict__ W2Rh, const _Float16* __restrict__ W2Rl,
    const float* __restrict__ b2,
    unsigned* __restrict__ bar)
{
    __shared__ float bch0[216];
    __shared__ float m4[136];
    __shared__ float ch0f[136];
    __shared__ __align__(16) _Float16 tTh[4 * 34 * 24];
    __shared__ __align__(16) _Float16 tTl[4 * 34 * 24];
    __shared__ __align__(16) _Float16 zero16[8];
    __shared__ __align__(16) _Float16 pH[64 * PK];
    __shared__ __align__(16) _Float16 pL[64 * PK];

    const int strip = blockIdx.x & 15;
    const int n = blockIdx.x >> 4;
    const int tid = threadIdx.x;
    const int r0 = strip * 2;

    const int wv = __builtin_amdgcn_readfirstlane(tid >> 6);  // 0..3
    const int lane = tid & 63;
    const int col = lane & 15;
    const int quad = lane >> 4;

    if (tid < 8) zero16[tid] = (_Float16)0.f;

    // ---- resident hi A-frags for G1 (56 VGPR) and G2 (32 VGPR)
    half8 A1h[NKS1][2];
    #pragma unroll
    for (int ks = 0; ks < NKS1; ++ks)
        #pragma unroll
        for (int i = 0; i < 2; ++i)
            A1h[ks][i] = *(const half8*)(WpRh + (((wv * 2 + i) * 7 + ks) * 64 + lane) * 8);
    half8 A2h[4][2];
    #pragma unroll
    for (int ks = 0; ks < 4; ++ks)
        #pragma unroll
        for (int i = 0; i < 2; ++i)
            A2h[ks][i] = *(const half8*)(W1Rh + (((wv * 2 + i) * 4 + ks) * 64 + lane) * 8);

    // ---- per-(ks,quad) fragment offset in tT; invalid -> zero line
    int koff[NKS1];
    #pragma unroll
    for (int ks = 0; ks < NKS1; ++ks) {
        int k0 = ks * 32 + quad * 8;
        int q = k0 / 24, c0 = k0 - q * 24;
        int dy = q / 3, dx = q - dy * 3;
        koff[ks] = (q < 9) ? (dy * 34 + dx) * 24 + c0 : -1;
    }
    int pbase[4];
    #pragma unroll
    for (int j = 0; j < 4; ++j) {
        int px = j * 16 + col;
        pbase[j] = ((px >> 5) * 34 + (px & 31)) * 24;
    }
    floatx4 biasP[2], biasH[2];
    #pragma unroll
    for (int i = 0; i < 2; ++i) {
        biasP[i] = *(const floatx4*)(bp + (wv * 2 + i) * 16 + quad * 4) * SCL;
        biasH[i] = *(const floatx4*)(b1 + (wv * 2 + i) * 16 + quad * 4) * SCL;
    }

    for (int s = 0; s < STEPS; ++s) {
        const float* Bn = (s & 1) ? B1g : B0g;
        float* Bo       = (s & 1) ? B0g : B1g;
        const unsigned char* Mi = (s & 1) ? M1g : M0g;
        unsigned char* Mo       = (s & 1) ? M0g : M1g;
        Bn += n * ST * PIX;
        Bo += n * ST * PIX;

        // ---- stage B ch0 with halo 2
        if (tid < 216) {
            int r = tid / 36, cq = tid % 36;
            int row = r0 - 2 + r, colg = cq - 2;
            float v = 0.f;
            if (row >= 0 && row < HW && colg >= 0 && colg < HW)
                v = Bn[row * HW + colg];
            bch0[tid] = v;
        }
        __syncthreads();

        // ---- combined mask m4 = Min & (maxpool3(B ch0) > TH); masked ch0 f32
        if (tid < 136) {
            int tr = tid / 34, tc = tid % 34;
            int y = r0 - 1 + tr, xc = tc - 1;
            float m = 0.f;
            if (y >= 0 && y < HW && xc >= 0 && xc < HW) {
                if (Mi[n * PIX + y * HW + xc]) {
                    float mx = -1e30f;
                    #pragma unroll
                    for (int dy = 0; dy < 3; ++dy)
                        #pragma unroll
                        for (int dx = 0; dx < 3; ++dx)
                            mx = fmaxf(mx, bch0[(tr + dy) * 36 + tc + dx]);
                    if (mx > TH) m = 1.f;
                }
            }
            m4[tid] = m;
            ch0f[tid] = bch0[(tr + 1) * 36 + (tc + 1)] * m;
        }
        __syncthreads();

        // ---- wave 0: next step's pre-mask from masked A ch0
        if (tid < 64) {
            int ry = lane >> 5, xx = lane & 31;
            float mx = -1e30f;
            #pragma unroll
            for (int dy = 0; dy < 3; ++dy)
                #pragma unroll
                for (int dx = 0; dx < 3; ++dx)
                    mx = fmaxf(mx, ch0f[(ry + dy) * 34 + xx + dx]);
            Mo[n * PIX + (r0 + ry) * HW + xx] = (mx > TH) ? 1 : 0;
        }

        // ---- stage transposed masked state/16 as fp16 hi/lo: tT[pix][c]
        for (int idx = tid; idx < 3264; idx += 256) {
            int c = idx % 24;
            int pix = idx / 24;
            float v = 0.f;
            if (c < ST) {
                int tr = pix / 34, tc = pix - tr * 34;
                int y = r0 - 1 + tr, xc = tc - 1;
                if (y >= 0 && y < HW && xc >= 0 && xc < HW)
                    v = Bn[c * PIX + y * HW + xc] * m4[pix];
            }
            float xs = v * SCL;
            _Float16 hi = (_Float16)xs;
            tTh[idx] = hi;
            tTl[idx] = (_Float16)(xs - (float)hi);
        }
        __syncthreads();

        // ---- GEMM 1: perc/16 = Wp @ tT, 2m x 4n per wave
        floatx4 acc1[2][4];
        #pragma unroll
        for (int i = 0; i < 2; ++i)
            #pragma unroll
            for (int j = 0; j < 4; ++j) acc1[i][j] = biasP[i];
        #pragma unroll
        for (int ks = 0; ks < NKS1; ++ks) {
            half8 Al[2];
            #pragma unroll
            for (int i = 0; i < 2; ++i)
                Al[i] = *(const half8*)(WpRl + (((wv * 2 + i) * 7 + ks) * 64 + lane) * 8);
            half8 bh[4], bl[4];
            #pragma unroll
            for (int j = 0; j < 4; ++j) {
                const _Float16* sh = (koff[ks] >= 0) ? (tTh + pbase[j] + koff[ks]) : zero16;
                const _Float16* sl = (koff[ks] >= 0) ? (tTl + pbase[j] + koff[ks]) : zero16;
                bh[j] = *(const half8*)sh;
                bl[j] = *(const half8*)sl;
            }
            #pragma unroll
            for (int i = 0; i < 2; ++i)
                #pragma unroll
                for (int j = 0; j < 4; ++j) {
                    acc1[i][j] = __builtin_amdgcn_mfma_f32_16x16x32_f16(A1h[ks][i], bh[j], acc1[i][j], 0, 0, 0);
                    acc1[i][j] = __builtin_amdgcn_mfma_f32_16x16x32_f16(A1h[ks][i], bl[j], acc1[i][j], 0, 0, 0);
                    acc1[i][j] = __builtin_amdgcn_mfma_f32_16x16x32_f16(Al[i],      bh[j], acc1[i][j], 0, 0, 0);
                }
        }
        #pragma unroll
        for (int i = 0; i < 2; ++i)
            #pragma unroll
            for (int j = 0; j < 4; ++j) {
                const int px = j * 16 + col;
                const int mb = (wv * 2 + i) * 16 + quad * 4;
                _Float16 h[4], l[4];
                #pragma unroll
                for (int r = 0; r < 4; ++r) {
                    h[r] = (_Float16)acc1[i][j][r];
                    l[r] = (_Float16)(acc1[i][j][r] - (float)h[r]);
                }
                *(half4v*)&pH[px * PK + mb] = (half4v){h[0], h[1], h[2], h[3]};
                *(half4v*)&pL[px * PK + mb] = (half4v){l[0], l[1], l[2], l[3]};
            }
        __syncthreads();

        // ---- GEMM 2: hid/16 = relu(W1 @ perc + b1)/16
        floatx4 acc2[2][4];
        #pragma unroll
        for (int i = 0; i < 2; ++i)
            #pragma unroll
            for (int j = 0; j < 4; ++j) acc2[i][j] = biasH[i];
        #pragma unroll
        for (int ks = 0; ks < 4; ++ks) {
            half8 Al[2];
            #pragma unroll
            for (int i = 0; i < 2; ++i)
                Al[i] = *(const half8*)(W1Rl + (((wv * 2 + i) * 4 + ks) * 64 + lane) * 8);
            half8 bh[4], bl[4];
            #pragma unroll
            for (int j = 0; j < 4; ++j) {
                const int px = j * 16 + col;
                bh[j] = *(const half8*)&pH[px * PK + ks * 32 + quad * 8];
                bl[j] = *(const half8*)&pL[px * PK + ks * 32 + quad * 8];
            }
            #pragma unroll
            for (int i = 0; i < 2; ++i)
                #pragma unroll
                for (int j = 0; j < 4; ++j) {
                    acc2[i][j] = __builtin_amdgcn_mfma_f32_16x16x32_f16(A2h[ks][i], bh[j], acc2[i][j], 0, 0, 0);
                    acc2[i][j] = __builtin_amdgcn_mfma_f32_16x16x32_f16(A2h[ks][i], bl[j], acc2[i][j], 0, 0, 0);
                    acc2[i][j] = __builtin_amdgcn_mfma_f32_16x16x32_f16(Al[i],      bh[j], acc2[i][j], 0, 0, 0);
                }
        }
        __syncthreads();                        // all perc reads complete
        #pragma unroll
        for (int i = 0; i < 2; ++i)
            #pragma unroll
            for (int j = 0; j < 4; ++j) {
                const int px = j * 16 + col;
                const int mb = (wv * 2 + i) * 16 + quad * 4;
                _Float16 h[4], l[4];
                #pragma unroll
                for (int r = 0; r < 4; ++r) {
                    float hv = fmaxf(acc2[i][j][r], 0.f);
                    h[r] = (_Float16)hv;
                    l[r] = (_Float16)(hv - (float)h[r]);
                }
                *(half4v*)&pH[px * PK + mb] = (half4v){h[0], h[1], h[2], h[3]};
                *(half4v*)&pL[px * PK + mb] = (half4v){l[0], l[1], l[2], l[3]};
            }
        __syncthreads();

        // ---- GEMM 3: upd = 16*(W2 @ hid/16) + b2; Bout = A + upd
        floatx4 accU[2];
        accU[0] = (floatx4){0.f, 0.f, 0.f, 0.f};
        accU[1] = (floatx4){0.f, 0.f, 0.f, 0.f};
        const int pxU = wv * 16 + col;
        #pragma unroll
        for (int ks = 0; ks < 4; ++ks) {
            half8 bh = *(const half8*)&pH[pxU * PK + ks * 32 + quad * 8];
            half8 bl = *(const half8*)&pL[pxU * PK + ks * 32 + quad * 8];
            #pragma unroll
            for (int mt = 0; mt < 2; ++mt) {
                half8 ah = *(const half8*)(W2Rh + ((mt * 4 + ks) * 64 + lane) * 8);
                half8 al = *(const half8*)(W2Rl + ((mt * 4 + ks) * 64 + lane) * 8);
                accU[mt] = __builtin_amdgcn_mfma_f32_16x16x32_f16(ah, bh, accU[mt], 0, 0, 0);
                accU[mt] = __builtin_amdgcn_mfma_f32_16x16x32_f16(ah, bl, accU[mt], 0, 0, 0);
                accU[mt] = __builtin_amdgcn_mfma_f32_16x16x32_f16(al, bh, accU[mt], 0, 0, 0);
            }
        }
        const int py = pxU >> 5, pxx = pxU & 31;
        const float mval = m4[(py + 1) * 34 + pxx + 1];
        #pragma unroll
        for (int mt = 0; mt < 2; ++mt)
            #pragma unroll
            for (int r = 0; r < 4; ++r) {
                int m = mt * 16 + quad * 4 + r;
                if (m < ST) {
                    float a = Bn[m * PIX + (r0 + py) * HW + pxx] * mval;
                    Bo[m * PIX + (r0 + py) * HW + pxx] = a + ISCL * accU[mt][r] + b2[m];
                }
            }

        // ---- device-scope grid barrier (per-step counter; ping-pong makes
        //      one-sided arrival safe). Skip after the last step.
        if (s != STEPS - 1) {
            __syncthreads();
            if (tid == 0) {
                __threadfence();
                __hip_atomic_fetch_add(&bar[s], 1u, __ATOMIC_ACQ_REL,
                                       __HIP_MEMORY_SCOPE_AGENT);
                unsigned t = 0;
                while (__hip_atomic_load(&bar[s], __ATOMIC_ACQUIRE,
                                         __HIP_MEMORY_SCOPE_AGENT) < NBLOCKS) {
                    __builtin_amdgcn_s_sleep(8);
                    if (++t > 1000000u) break;   // hang safety valve
                }
            }
            __syncthreads();
        }
    }
}

// ---------------------------------------------------------------------------
__global__ __launch_bounds__(256) void finalize_kernel(
    const float* __restrict__ B, const unsigned char* __restrict__ M,
    float* __restrict__ out)
{
    const int n = blockIdx.y;
    const int p = blockIdx.x * 256 + threadIdx.x;
    const int y = p >> 5, x = p & 31;
    const float* Bn = B + n * ST * PIX;
    float m = 0.f;
    if (M[n * PIX + p]) {
        float mx = -1e30f;
        for (int dy = -1; dy <= 1; ++dy) {
            int yy = y + dy; if (yy < 0 || yy >= HW) continue;
            for (int dx = -1; dx <= 1; ++dx) {
                int xx = x + dx; if (xx < 0 || xx >= HW) continue;
                mx = fmaxf(mx, Bn[yy * HW + xx]);
            }
        }
        if (mx > TH) m = 1.f;
    }
    out[n * PIX + p] = Bn[p] * m;
}

// ---------------------------------------------------------------------------
extern "C" void kernel_launch(void* const* d_in, const int* in_sizes, int n_in,
                              void* d_out, int out_size, void* d_ws, size_t ws_size,
                              hipStream_t stream)
{
    const float* z       = (const float*)d_in[0];
    const float* w_init1 = (const float*)d_in[1];
    const float* b_init1 = (const float*)d_in[2];
    const float* w_init2 = (const float*)d_in[3];
    const float* b_init2 = (const float*)d_in[4];
    const float* w_perc  = (const float*)d_in[5];
    const float* b_perc  = (const float*)d_in[6];
    const float* w_up1   = (const float*)d_in[7];
    const float* b_up1   = (const float*)d_in[8];
    const float* w_up2   = (const float*)d_in[9];
    const float* b_up2   = (const float*)d_in[10];

    float* B0 = (float*)d_ws;
    float* B1 = B0 + NB * ST * PIX;
    unsigned char* M0 = (unsigned char*)(B1 + NB * ST * PIX);
    unsigned char* M1 = M0 + NB * PIX;
    _Float16* WpRh = (_Float16*)(M1 + NB * PIX);
    _Float16* WpRl = WpRh + 28672;
    _Float16* W1Rh = WpRl + 28672;
    _Float16* W1Rl = W1Rh + 16384;
    _Float16* W2Rh = W1Rl + 16384;
    _Float16* W2Rl = W2Rh + 4096;
    unsigned* bar  = (unsigned*)(W2Rl + 4096);     // 64 step counters

    hipMemsetAsync(bar, 0, STEPS * sizeof(unsigned), stream);
    hipMemsetAsync(B0, 0, (size_t)NB * ST * PIX * sizeof(float), stream);
    repack_kernel<<<192, 256, 0, stream>>>(w_perc, w_up1, w_up2,
                                           WpRh, WpRl, W1Rh, W1Rl, W2Rh, W2Rl);
    init_state_kernel<<<NB, 64, 0, stream>>>(z, w_init1, b_init1, w_init2,
                                             b_init2, B0, M0);

    ca_persistent_kernel<<<NBLOCKS, 256, 0, stream>>>(
        B0, B1, M0, M1, WpRh, WpRl, b_perc, W1Rh, W1Rl, b_up1,
        W2Rh, W2Rl, b_up2, bar);

    // 64 steps (even) -> final state in (B0, M0)
    finalize_kernel<<<dim3(4, NB), 256, 0, stream>>>(B0, M0, (float*)d_out);
}

// Round 7
// 947.036 us; speedup vs baseline: 5.5051x; 5.5051x over previous
//
#include <hip/hip_runtime.h>

#define NB 32
#define NZ 100
#define ST 20
#define HID 128
#define HW 32
#define PIX 1024
#define STEPS 64
#define TH 0.1f
#define SCL 0.0625f     // 1/16 stored-value scaling (power of 2)
#define ISCL 16.0f

typedef _Float16 half8  __attribute__((ext_vector_type(8)));
typedef _Float16 half4v __attribute__((ext_vector_type(4)));
typedef float    floatx4 __attribute__((ext_vector_type(4)));

// perceive GEMM K layout: k = q*24 + c  (q=dy*3+dx in 0..8, c in 0..23, pad from 20)
#define NKS1 7
#define PK 136          // perc/hid LDS row stride (68 words: 4i-bank pattern, 2-way = free)

// ---------------------------------------------------------------------------
__global__ __launch_bounds__(64) void init_state_kernel(
    const float* __restrict__ z, const float* __restrict__ w1,
    const float* __restrict__ b1, const float* __restrict__ w2,
    const float* __restrict__ b2, float* __restrict__ B,
    unsigned char* __restrict__ M)
{
    __shared__ float zs[NZ];
    __shared__ float h1[50];
    const int n = blockIdx.x;
    const int t = threadIdx.x;
    for (int i = t; i < NZ; i += 64) zs[i] = z[n * NZ + i];
    __syncthreads();
    if (t < 50) {
        float a = b1[t];
        for (int i = 0; i < NZ; ++i) a += w1[t * NZ + i] * zs[i];
        h1[t] = fmaxf(a, 0.f);
    }
    __syncthreads();
    if (t < ST - 1) {
        float a = b2[t];
        for (int j = 0; j < 50; ++j) a += w2[t * 50 + j] * h1[j];
        B[n * ST * PIX + (t + 1) * PIX + 16 * HW + 16] = a;
    }
    if (t == 63) B[n * ST * PIX + 16 * HW + 16] = 0.5f;
    for (int i = t; i < PIX; i += 64) M[n * PIX + i] = 1;
}

// ---------------------------------------------------------------------------
// Repack weights into MFMA A-fragment order as fp16 hi/lo pairs. (unchanged)
__global__ __launch_bounds__(256) void repack_kernel(
    const float* __restrict__ Wp, const float* __restrict__ W1,
    const float* __restrict__ W2,
    _Float16* __restrict__ WpRh, _Float16* __restrict__ WpRl,
    _Float16* __restrict__ W1Rh, _Float16* __restrict__ W1Rl,
    _Float16* __restrict__ W2Rh, _Float16* __restrict__ W2Rl)
{
    int e = blockIdx.x * 256 + threadIdx.x;
    if (e < 28672) {
        int j = e & 7, lane = (e >> 3) & 63, t2 = e >> 9;   // t2 = w*7+ks
        int ks = t2 % 7, w = t2 / 7;
        int m = w * 16 + (lane & 15);
        int k = ks * 32 + ((lane >> 4) << 3) + j;
        int q = k / 24, c = k - q * 24;
        float v = (q < 9 && c < ST) ? Wp[m * 180 + c * 9 + q] : 0.f;
        _Float16 hi = (_Float16)v;
        WpRh[e] = hi; WpRl[e] = (_Float16)(v - (float)hi);
    } else if (e < 45056) {
        int e2 = e - 28672;
        int j = e2 & 7, lane = (e2 >> 3) & 63, t2 = e2 >> 9; // t2 = w*4+ks
        int ks = t2 & 3, w = t2 >> 2;
        int m = w * 16 + (lane & 15);
        int k = ks * 32 + ((lane >> 4) << 3) + j;
        float v = W1[m * 128 + k];
        _Float16 hi = (_Float16)v;
        W1Rh[e2] = hi; W1Rl[e2] = (_Float16)(v - (float)hi);
    } else if (e < 49152) {
        int e3 = e - 45056;
        int j = e3 & 7, lane = (e3 >> 3) & 63, t2 = e3 >> 9; // t2 = mt*4+ks
        int ks = t2 & 3, mt = t2 >> 2;
        int m = mt * 16 + (lane & 15);
        int k = ks * 32 + ((lane >> 4) << 3) + j;
        float v = (m < ST) ? W2[m * 128 + k] : 0.f;
        _Float16 hi = (_Float16)v;
        W2Rh[e3] = hi; W2Rl[e3] = (_Float16)(v - (float)hi);
    }
}

// ---------------------------------------------------------------------------
// Fused CA step (split-fp16 MFMA, 4Mx2N wave tiling).
// Changes vs R5: G2 weights streamed (VGPR<=128 -> 2 blocks/CU guaranteed),
// G3 deduplicated (wave = one (mt,nt) pair), Min/state prefetched into regs.
__global__ __launch_bounds__(512, 4) void ca_step_kernel(
    const float* __restrict__ Bin, const unsigned char* __restrict__ Min,
    float* __restrict__ Bout, unsigned char* __restrict__ Mout,
    const _Float16* __restrict__ WpRh, const _Float16* __restrict__ WpRl,
    const float* __restrict__ bp,
    const _Float16* __restrict__ W1Rh, const _Float16* __restrict__ W1Rl,
    const float* __restrict__ b1,
    const _Float16* __restrict__ W2Rh, const _Float16* __restrict__ W2Rl,
    const float* __restrict__ b2)
{
    __shared__ float bch0[216];
    __shared__ float m4[136];
    __shared__ float ch0f[136];
    __shared__ __align__(16) _Float16 tTh[4 * 34 * 24];
    __shared__ __align__(16) _Float16 tTl[4 * 34 * 24];
    __shared__ __align__(16) _Float16 zero16[8];
    __shared__ __align__(16) _Float16 pH[64 * PK];
    __shared__ __align__(16) _Float16 pL[64 * PK];

    const int strip = blockIdx.x;
    const int n = blockIdx.y;
    const int tid = threadIdx.x;
    const int r0 = strip * 2;
    const float* Bn = Bin + n * ST * PIX;

    const int wv = __builtin_amdgcn_readfirstlane(tid >> 6);
    const int lane = tid & 63;
    const int col = lane & 15;
    const int quad = lane >> 4;
    const int wm = wv >> 1;            // 0..3 : M-split (2 m-tiles each)
    const int wn = wv & 1;             // 0..1 : N-split (2 n-tiles each)

    // ---- phase A: stage B ch0 (halo 2) + prefetch Min & tT state into regs
    if (tid < 216) {
        int r = tid / 36, cq = tid % 36;
        int row = r0 - 2 + r, colg = cq - 2;
        float v = 0.f;
        if (row >= 0 && row < HW && colg >= 0 && colg < HW) v = Bn[row * HW + colg];
        bch0[tid] = v;
    }
    unsigned char minb = 0;
    if (tid < 136) {
        int tr = tid / 34, tc = tid % 34;
        int y = r0 - 1 + tr, xc = tc - 1;
        if (y >= 0 && y < HW && xc >= 0 && xc < HW)
            minb = Min[n * PIX + y * HW + xc];
    }
    float stv[7];
    #pragma unroll
    for (int k = 0; k < 7; ++k) {
        int idx = tid + 512 * k;
        float v = 0.f;
        if (idx < 3264) {
            int c = idx % 24;
            int pix = idx / 24;
            if (c < ST) {
                int tr = pix / 34, tc = pix - tr * 34;
                int y = r0 - 1 + tr, xc = tc - 1;
                if (y >= 0 && y < HW && xc >= 0 && xc < HW)
                    v = Bn[c * PIX + y * HW + xc];
            }
        }
        stv[k] = v;
    }
    if (tid < 8) zero16[tid] = (_Float16)0.f;
    __syncthreads();

    // ---- phase B: combined mask m4 = Min & (maxpool3(B ch0) > TH); masked ch0
    if (tid < 136) {
        int tr = tid / 34, tc = tid % 34;
        float m = 0.f;
        if (minb) {
            float mx = -1e30f;
            #pragma unroll
            for (int dy = 0; dy < 3; ++dy)
                #pragma unroll
                for (int dx = 0; dx < 3; ++dx)
                    mx = fmaxf(mx, bch0[(tr + dy) * 36 + tc + dx]);
            if (mx > TH) m = 1.f;
        }
        m4[tid] = m;
        ch0f[tid] = bch0[(tr + 1) * 36 + (tc + 1)] * m;
    }
    __syncthreads();

    // ---- phase C: tT from prefetched regs * mask; wave0 also next pre-mask
    #pragma unroll
    for (int k = 0; k < 7; ++k) {
        int idx = tid + 512 * k;
        if (idx < 3264) {
            int pix = idx / 24;
            float xs = stv[k] * m4[pix] * SCL;
            _Float16 hi = (_Float16)xs;
            tTh[idx] = hi;
            tTl[idx] = (_Float16)(xs - (float)hi);
        }
    }
    if (tid < 64) {
        int ry = lane >> 5, xx = lane & 31;
        float mx = -1e30f;
        #pragma unroll
        for (int dy = 0; dy < 3; ++dy)
            #pragma unroll
            for (int dx = 0; dx < 3; ++dx)
                mx = fmaxf(mx, ch0f[(ry + dy) * 34 + xx + dx]);
        Mout[n * PIX + (r0 + ry) * HW + xx] = (mx > TH) ? 1 : 0;
    }
    __syncthreads();

    // ---- per-(ks,quad) fragment offset in tT; invalid -> zero line
    int koff[NKS1];
    #pragma unroll
    for (int ks = 0; ks < NKS1; ++ks) {
        int k0 = ks * 32 + quad * 8;
        int q = k0 / 24, c0 = k0 - q * 24;
        int dy = q / 3, dx = q - dy * 3;
        koff[ks] = (q < 9) ? (dy * 34 + dx) * 24 + c0 : -1;
    }
    int pbase[2];
    #pragma unroll
    for (int j = 0; j < 2; ++j) {
        int px = (wn * 2 + j) * 16 + col;
        pbase[j] = ((px >> 5) * 34 + (px & 31)) * 24;
    }

    // ---- GEMM 1: perc/16 = Wp @ tT, 2m x 2n per wave; A-hi resident
    floatx4 acc1[2][2];
    #pragma unroll
    for (int i = 0; i < 2; ++i) {
        floatx4 b = *(const floatx4*)(bp + (wm * 2 + i) * 16 + quad * 4) * SCL;
        acc1[i][0] = b; acc1[i][1] = b;
    }
    #pragma unroll
    for (int ks = 0; ks < NKS1; ++ks) {
        half8 Ah[2], Al[2];
        #pragma unroll
        for (int i = 0; i < 2; ++i) {
            int mt = wm * 2 + i;
            Ah[i] = *(const half8*)(WpRh + ((mt * 7 + ks) * 64 + lane) * 8);
            Al[i] = *(const half8*)(WpRl + ((mt * 7 + ks) * 64 + lane) * 8);
        }
        half8 bh[2], bl[2];
        #pragma unroll
        for (int j = 0; j < 2; ++j) {
            const _Float16* sh = (koff[ks] >= 0) ? (tTh + pbase[j] + koff[ks]) : zero16;
            const _Float16* sl = (koff[ks] >= 0) ? (tTl + pbase[j] + koff[ks]) : zero16;
            bh[j] = *(const half8*)sh;
            bl[j] = *(const half8*)sl;
        }
        #pragma unroll
        for (int i = 0; i < 2; ++i)
            #pragma unroll
            for (int j = 0; j < 2; ++j) {
                acc1[i][j] = __builtin_amdgcn_mfma_f32_16x16x32_f16(Ah[i], bh[j], acc1[i][j], 0, 0, 0);
                acc1[i][j] = __builtin_amdgcn_mfma_f32_16x16x32_f16(Ah[i], bl[j], acc1[i][j], 0, 0, 0);
                acc1[i][j] = __builtin_amdgcn_mfma_f32_16x16x32_f16(Al[i], bh[j], acc1[i][j], 0, 0, 0);
            }
    }
    #pragma unroll
    for (int i = 0; i < 2; ++i)
        #pragma unroll
        for (int j = 0; j < 2; ++j) {
            const int px = (wn * 2 + j) * 16 + col;
            const int mb = (wm * 2 + i) * 16 + quad * 4;
            _Float16 h[4], l[4];
            #pragma unroll
            for (int r = 0; r < 4; ++r) {
                h[r] = (_Float16)acc1[i][j][r];
                l[r] = (_Float16)(acc1[i][j][r] - (float)h[r]);
            }
            *(half4v*)&pH[px * PK + mb] = (half4v){h[0], h[1], h[2], h[3]};
            *(half4v*)&pL[px * PK + mb] = (half4v){l[0], l[1], l[2], l[3]};
        }
    __syncthreads();

    // ---- GEMM 2: hid/16 = relu(W1 @ perc + b1)/16; W1 hi+lo streamed from L2
    floatx4 acc2[2][2];
    #pragma unroll
    for (int i = 0; i < 2; ++i) {
        floatx4 b = *(const floatx4*)(b1 + (wm * 2 + i) * 16 + quad * 4) * SCL;
        acc2[i][0] = b; acc2[i][1] = b;
    }
    #pragma unroll
    for (int ks = 0; ks < 4; ++ks) {
        half8 Ah[2], Al[2];
        #pragma unroll
        for (int i = 0; i < 2; ++i) {
            int mt = wm * 2 + i;
            Ah[i] = *(const half8*)(W1Rh + ((mt * 4 + ks) * 64 + lane) * 8);
            Al[i] = *(const half8*)(W1Rl + ((mt * 4 + ks) * 64 + lane) * 8);
        }
        half8 bh[2], bl[2];
        #pragma unroll
        for (int j = 0; j < 2; ++j) {
            const int px = (wn * 2 + j) * 16 + col;
            bh[j] = *(const half8*)&pH[px * PK + ks * 32 + quad * 8];
            bl[j] = *(const half8*)&pL[px * PK + ks * 32 + quad * 8];
        }
        #pragma unroll
        for (int i = 0; i < 2; ++i)
            #pragma unroll
            for (int j = 0; j < 2; ++j) {
                acc2[i][j] = __builtin_amdgcn_mfma_f32_16x16x32_f16(Ah[i], bh[j], acc2[i][j], 0, 0, 0);
                acc2[i][j] = __builtin_amdgcn_mfma_f32_16x16x32_f16(Ah[i], bl[j], acc2[i][j], 0, 0, 0);
                acc2[i][j] = __builtin_amdgcn_mfma_f32_16x16x32_f16(Al[i], bh[j], acc2[i][j], 0, 0, 0);
            }
    }
    __syncthreads();                        // all perc reads complete
    #pragma unroll
    for (int i = 0; i < 2; ++i)
        #pragma unroll
        for (int j = 0; j < 2; ++j) {
            const int px = (wn * 2 + j) * 16 + col;
            const int mb = (wm * 2 + i) * 16 + quad * 4;
            _Float16 h[4], l[4];
            #pragma unroll
            for (int r = 0; r < 4; ++r) {
                float hv = fmaxf(acc2[i][j][r], 0.f);
                h[r] = (_Float16)hv;
                l[r] = (_Float16)(hv - (float)h[r]);
            }
            *(half4v*)&pH[px * PK + mb] = (half4v){h[0], h[1], h[2], h[3]};
            *(half4v*)&pL[px * PK + mb] = (half4v){l[0], l[1], l[2], l[3]};
        }
    __syncthreads();

    // ---- GEMM 3 (dedup): wave = (mt = wv&1, nt = wv>>1); upd = 16*(W2@hid/16)+b2
    const int mt3 = wv & 1, ntU = wv >> 1;
    floatx4 accU = {0.f, 0.f, 0.f, 0.f};
    const int pxU = ntU * 16 + col;
    #pragma unroll
    for (int ks = 0; ks < 4; ++ks) {
        half8 ah = *(const half8*)(W2Rh + ((mt3 * 4 + ks) * 64 + lane) * 8);
        half8 al = *(const half8*)(W2Rl + ((mt3 * 4 + ks) * 64 + lane) * 8);
        half8 bh = *(const half8*)&pH[pxU * PK + ks * 32 + quad * 8];
        half8 bl = *(const half8*)&pL[pxU * PK + ks * 32 + quad * 8];
        accU = __builtin_amdgcn_mfma_f32_16x16x32_f16(ah, bh, accU, 0, 0, 0);
        accU = __builtin_amdgcn_mfma_f32_16x16x32_f16(ah, bl, accU, 0, 0, 0);
        accU = __builtin_amdgcn_mfma_f32_16x16x32_f16(al, bh, accU, 0, 0, 0);
    }
    const int py = pxU >> 5, pxx = pxU & 31;
    const float mval = m4[(py + 1) * 34 + pxx + 1];
    float* Bo = Bout + n * ST * PIX;
    #pragma unroll
    for (int r = 0; r < 4; ++r) {
        int m = mt3 * 16 + quad * 4 + r;
        if (m < ST) {
            float a = Bn[m * PIX + (r0 + py) * HW + pxx] * mval;
            Bo[m * PIX + (r0 + py) * HW + pxx] = a + ISCL * accU[r] + b2[m];
        }
    }
}

// ---------------------------------------------------------------------------
__global__ __launch_bounds__(256) void finalize_kernel(
    const float* __restrict__ B, const unsigned char* __restrict__ M,
    float* __restrict__ out)
{
    const int n = blockIdx.y;
    const int p = blockIdx.x * 256 + threadIdx.x;
    const int y = p >> 5, x = p & 31;
    const float* Bn = B + n * ST * PIX;
    float m = 0.f;
    if (M[n * PIX + p]) {
        float mx = -1e30f;
        for (int dy = -1; dy <= 1; ++dy) {
            int yy = y + dy; if (yy < 0 || yy >= HW) continue;
            for (int dx = -1; dx <= 1; ++dx) {
                int xx = x + dx; if (xx < 0 || xx >= HW) continue;
                mx = fmaxf(mx, Bn[yy * HW + xx]);
            }
        }
        if (mx > TH) m = 1.f;
    }
    out[n * PIX + p] = Bn[p] * m;
}

// ---------------------------------------------------------------------------
extern "C" void kernel_launch(void* const* d_in, const int* in_sizes, int n_in,
                              void* d_out, int out_size, void* d_ws, size_t ws_size,
                              hipStream_t stream)
{
    const float* z       = (const float*)d_in[0];
    const float* w_init1 = (const float*)d_in[1];
    const float* b_init1 = (const float*)d_in[2];
    const float* w_init2 = (const float*)d_in[3];
    const float* b_init2 = (const float*)d_in[4];
    const float* w_perc  = (const float*)d_in[5];
    const float* b_perc  = (const float*)d_in[6];
    const float* w_up1   = (const float*)d_in[7];
    const float* b_up1   = (const float*)d_in[8];
    const float* w_up2   = (const float*)d_in[9];
    const float* b_up2   = (const float*)d_in[10];

    float* B0 = (float*)d_ws;
    float* B1 = B0 + NB * ST * PIX;
    unsigned char* M0 = (unsigned char*)(B1 + NB * ST * PIX);
    unsigned char* M1 = M0 + NB * PIX;
    _Float16* WpRh = (_Float16*)(M1 + NB * PIX);
    _Float16* WpRl = WpRh + 28672;
    _Float16* W1Rh = WpRl + 28672;
    _Float16* W1Rl = W1Rh + 16384;
    _Float16* W2Rh = W1Rl + 16384;
    _Float16* W2Rl = W2Rh + 4096;

    repack_kernel<<<192, 256, 0, stream>>>(w_perc, w_up1, w_up2,
                                           WpRh, WpRl, W1Rh, W1Rl, W2Rh, W2Rl);
    hipMemsetAsync(B0, 0, (size_t)NB * ST * PIX * sizeof(float), stream);
    init_state_kernel<<<NB, 64, 0, stream>>>(z, w_init1, b_init1, w_init2,
                                             b_init2, B0, M0);

    for (int s = 0; s < STEPS; ++s) {
        const float* bi = (s & 1) ? B1 : B0;
        float* bo       = (s & 1) ? B0 : B1;
        const unsigned char* mi = (s & 1) ? M1 : M0;
        unsigned char* mo       = (s & 1) ? M0 : M1;
        ca_step_kernel<<<dim3(16, NB), 512, 0, stream>>>(
            bi, mi, bo, mo, WpRh, WpRl, b_perc, W1Rh, W1Rl, b_up1,
            W2Rh, W2Rl, b_up2);
    }
    // 64 steps (even) -> final state in (B0, M0)
    finalize_kernel<<<dim3(4, NB), 256, 0, stream>>>(B0, M0, (float*)d_out);
}